// Round 11
// baseline (37.462 us; speedup 1.0000x reference)
//
#include <hip/hip_runtime.h>

#define HWC 16384      // H*W
#define WD  128
#define NC  64
#define EPSV 1e-6f

typedef __attribute__((ext_vector_type(8))) short bf16x8;
typedef __attribute__((ext_vector_type(4))) float f32x4;
typedef __attribute__((ext_vector_type(4))) unsigned int u32x4;

__device__ __forceinline__ unsigned short f2bf(float f) {
  unsigned u = __builtin_bit_cast(unsigned, f);
  u = (u + 0x7FFFu + ((u >> 16) & 1u)) >> 16;   // RNE
  return (unsigned short)u;
}
__device__ __forceinline__ float bfLo(unsigned pk) { return __builtin_bit_cast(float, pk << 16); }
__device__ __forceinline__ float bfHi(unsigned pk) { return __builtin_bit_cast(float, pk & 0xFFFF0000u); }
// XOR swizzle for 128-B-row bf16 tiles.
__device__ __forceinline__ int swz(int row, int colbytes) {
  return ((row << 7) + colbytes) ^ ((row & 7) << 4);
}
__device__ __forceinline__ bf16x8 pack8(float4 a, float4 b) {
  bf16x8 r;
  r[0] = (short)f2bf(a.x); r[1] = (short)f2bf(a.y);
  r[2] = (short)f2bf(a.z); r[3] = (short)f2bf(a.w);
  r[4] = (short)f2bf(b.x); r[5] = (short)f2bf(b.y);
  r[6] = (short)f2bf(b.z); r[7] = (short)f2bf(b.w);
  return r;
}

// Fully fused head->NMF->tail, 3-barrier chain. grid 1024 (b,y,seg); 512 thr.
// NMF: thread owns (px = 8wv + lane>>3, channels 8cg..+8, cg = lane&7);
// cross-channel reduce = 3x shfl_xor (no LDS, no barriers).
__global__ __launch_bounds__(512, 4) void k_fused(const float* __restrict__ x,
                                                  const float* __restrict__ Wh,
                                                  const float* __restrict__ Wt,
                                                  float* __restrict__ out) {
  __shared__ __align__(16) char smem[53248];
  unsigned short* xt = (unsigned short*)smem;            // [208 sites][64 c], 26624 B
  unsigned short* hl = (unsigned short*)(smem + 26624);  // [208 sites][64 o], 26624 B
  unsigned short* uvb = (unsigned short*)smem;           // overlay on xt (dead after head)

  const int t = threadIdx.x, lane = t & 63, wv = t >> 6;
  const int bid0 = blockIdx.x;
  const int bid = ((bid0 & 7) << 7) | (bid0 >> 3);  // XCD swizzle, bijective (1024%8==0)
  const int seg = bid & 1, y = (bid >> 1) & 127, b = bid >> 8;
  const int w0 = seg << 6;
  const int c0 = wv << 3;            // stage channel base
  const int l15 = lane & 15, kg = lane >> 4;
  const int mt = wv & 3;
  const int mrow = (mt << 4) + l15;
  const int n0 = (wv >> 2) << 1;

  int gy[3];
  gy[0] = y >= 2 ? y - 2 : 0;
  gy[1] = y;
  gy[2] = y <= 125 ? y + 2 : 127;

  const float* xb = x + (size_t)b * (NC * HWC);
  const size_t gb = (size_t)b * (NC * HWC) + (size_t)y * WD + w0;

  // ---- head A fragments from global Wh (L2-resident) ----
  bf16x8 ha0, ha1;
  {
    const float* wr = Wh + mrow * 64 + kg * 8;
    ha0 = pack8(*(const float4*)wr, *(const float4*)(wr + 4));
    ha1 = pack8(*(const float4*)(wr + 32), *(const float4*)(wr + 36));
  }

  // ---- residual prefetch: same cache lines the stage is fetching (L1-hot) ----
  float resv[2][4];
#pragma unroll
  for (int q = 0; q < 2; ++q) {
    const int px = ((n0 + q) << 4) + l15;
#pragma unroll
    for (int j = 0; j < 4; ++j) {
      const int c2 = (mt << 4) + kg * 4 + j;
      resv[q][j] = x[gb + (size_t)c2 * HWC + px];
    }
  }

  // ---- stage xt[site][ch]: site s = r*68+i <-> (row gy[r], col clamp(w0-2+i)) ----
  {
    int colm = w0 - 2 + lane; if (colm < 0) colm = 0;
#pragma unroll
    for (int r = 0; r < 3; ++r) {
      const float* xr = xb + gy[r] * WD + colm;
      bf16x8 v;
#pragma unroll
      for (int u = 0; u < 8; ++u) v[u] = (short)f2bf(xr[(size_t)(c0 + u) * HWC]);
      *(bf16x8*)((char*)xt + swz(r * 68 + lane, c0 * 2)) = v;
    }
    if (lane < 12) {   // extra cols i=64..67
      const int re = lane >> 2, e = lane & 3;
      int cole = w0 + 62 + e; if (cole > 127) cole = 127;
      const float* xr = xb + gy[re] * WD + cole;
      bf16x8 v;
#pragma unroll
      for (int u = 0; u < 8; ++u) v[u] = (short)f2bf(xr[(size_t)(c0 + u) * HWC]);
      *(bf16x8*)((char*)xt + swz(re * 68 + 64 + e, c0 * 2)) = v;
    }
  }
  __syncthreads();   // (1)

  // ---- head MFMA: compile-time-unrolled N-tile loops; ReLU; uint2 -> hl ----
#define HEAD_STEP(NT)                                                            \
  {                                                                              \
    const int s = ((NT) << 4) + l15;                                             \
    const bf16x8 b0 = *(const bf16x8*)((char*)xt + swz(s, kg * 16));             \
    const bf16x8 b1 = *(const bf16x8*)((char*)xt + swz(s, 64 + kg * 16));        \
    f32x4 acc = __builtin_amdgcn_mfma_f32_16x16x32_bf16(ha0, b0, zz, 0, 0, 0);   \
    acc = __builtin_amdgcn_mfma_f32_16x16x32_bf16(ha1, b1, acc, 0, 0, 0);        \
    const float v0 = acc[0] > 0.f ? acc[0] : 0.f;                                \
    const float v1 = acc[1] > 0.f ? acc[1] : 0.f;                                \
    const float v2 = acc[2] > 0.f ? acc[2] : 0.f;                                \
    const float v3 = acc[3] > 0.f ? acc[3] : 0.f;                                \
    uint2 pk2;                                                                   \
    pk2.x = (unsigned)f2bf(v0) | ((unsigned)f2bf(v1) << 16);                     \
    pk2.y = (unsigned)f2bf(v2) | ((unsigned)f2bf(v3) << 16);                     \
    *(uint2*)((char*)hl + swz(s, (mt * 16 + kg * 4) * 2)) = pk2;                 \
  }
  {
    const f32x4 zz = {0.f, 0.f, 0.f, 0.f};
    if (wv < 4) {
#pragma unroll
      for (int nt = 0; nt < 7; ++nt) HEAD_STEP(nt)
    } else {
#pragma unroll
      for (int nt = 7; nt < 13; ++nt) HEAD_STEP(nt)
    }
  }
#undef HEAD_STEP
  __syncthreads();   // (2)

  // ---- NMF pass 1: 9 b128 tap reads (8 ch each); shfl_xor reduce ----
  const int pxn = (wv << 3) | (lane >> 3);   // this thread's pixel
  const int cb2 = (lane & 7) << 4;           // channel-group colbytes
  u32x4 tap[9];
#pragma unroll
  for (int r = 0; r < 3; ++r)
#pragma unroll
    for (int kc = 0; kc < 3; ++kc)
      tap[r * 3 + kc] = *(const u32x4*)((char*)hl + swz(r * 68 + pxn + 2 * kc, cb2));

  float S = 0.f, sumk[9], A[9], mreg[8];
#pragma unroll
  for (int k = 0; k < 9; ++k) { sumk[k] = 0.f; A[k] = 0.f; }
#pragma unroll
  for (int c = 0; c < 8; ++c) {
    float tc[9];
#pragma unroll
    for (int k = 0; k < 9; ++k) {
      const unsigned w32 = tap[k][c >> 1];
      tc[k] = (c & 1) ? bfHi(w32) : bfLo(w32);
    }
    float m = 0.f;
#pragma unroll
    for (int k = 0; k < 9; ++k) m += tc[k];
    m *= (1.f / 9.f);
    mreg[c] = m;
    S += m * m;
#pragma unroll
    for (int k = 0; k < 9; ++k) { sumk[k] += tc[k]; A[k] += m * tc[k]; }
  }

  // ---- butterfly reduce over the 8 channel-group lanes (xor 1,2,4) ----
#pragma unroll
  for (int d = 1; d <= 4; d <<= 1) {
    S += __shfl_xor(S, d);
#pragma unroll
    for (int k = 0; k < 9; ++k) sumk[k] += __shfl_xor(sumk[k], d);
#pragma unroll
    for (int k = 0; k < 9; ++k) A[k] += __shfl_xor(A[k], d);
  }

  float Vk[9], T = 0.f;
#pragma unroll
  for (int k = 0; k < 9; ++k) {
    const float nk = sumk[k] * (1.f / 64.f);
    Vk[k] = nk * (A[k] / (3.f * nk * S + EPSV));
    T += Vk[k] * Vk[k];
  }
  const float V4 = Vk[4];

  // ---- tail A fragments from global Wt (hides under pass 2) ----
  bf16x8 ta0, ta1;
  {
    const float* wr = Wt + mrow * 64 + kg * 8;
    ta0 = pack8(*(const float4*)wr, *(const float4*)(wr + 4));
    ta1 = pack8(*(const float4*)(wr + 32), *(const float4*)(wr + 36));
  }

  // ---- pass 2: pure VALU from cached taps; b128 UV write into uvb@xt ----
  {
    bf16x8 vv;
#pragma unroll
    for (int c = 0; c < 8; ++c) {
      float Bc = 0.f;
#pragma unroll
      for (int k = 0; k < 9; ++k) {
        const unsigned w32 = tap[k][c >> 1];
        const float tk = (c & 1) ? bfHi(w32) : bfLo(w32);
        Bc += tk * Vk[k];
      }
      const float m = mreg[c];
      const float Uc = m * (Bc / (3.f * m * T + EPSV));
      vv[c] = (short)f2bf(3.f * Uc * V4);
    }
    *(bf16x8*)((char*)uvb + swz(pxn, cb2)) = vv;   // [px][o]
  }
  __syncthreads();   // (3)

  // ---- tail MFMA: M-tile mt, N-tiles {n0, n0+1}; + prefetched residual ----
  const f32x4 z2 = {0.f, 0.f, 0.f, 0.f};
#pragma unroll
  for (int q = 0; q < 2; ++q) {
    const int px = ((n0 + q) << 4) + l15;
    const bf16x8 b0 = *(const bf16x8*)((char*)uvb + swz(px, kg * 16));
    const bf16x8 b1 = *(const bf16x8*)((char*)uvb + swz(px, 64 + kg * 16));
    f32x4 acc = __builtin_amdgcn_mfma_f32_16x16x32_bf16(ta0, b0, z2, 0, 0, 0);
    acc = __builtin_amdgcn_mfma_f32_16x16x32_bf16(ta1, b1, acc, 0, 0, 0);
#pragma unroll
    for (int j = 0; j < 4; ++j) {
      const int c2 = (mt << 4) + kg * 4 + j;
      const size_t off = gb + (size_t)c2 * HWC + px;
      out[off] = acc[j] + resv[q][j];
    }
  }
}

extern "C" void kernel_launch(void* const* d_in, const int* in_sizes, int n_in,
                              void* d_out, int out_size, void* d_ws, size_t ws_size,
                              hipStream_t stream) {
  const float* x  = (const float*)d_in[0];
  const float* Wh = (const float*)d_in[1];
  const float* Wt = (const float*)d_in[2];
  float* out = (float*)d_out;

  k_fused<<<1024, 512, 0, stream>>>(x, Wh, Wt, out);
}